// Round 1
// baseline (239.211 us; speedup 1.0000x reference)
//
#include <hip/hip_runtime.h>
#include <math.h>

#define N_CH 128

// ---------------------------------------------------------------------------
// K0: build V1t[k*128+o] = W[o][k] - W[o][128+k], V2t[k*128+o] = W[o][128+k]
//     (k-major so GEMM reads of V are lane-coalesced) and zero the histogram.
// ---------------------------------------------------------------------------
__global__ __launch_bounds__(256) void prep_kernel(const float* __restrict__ W,
                                                   float* __restrict__ V1,
                                                   float* __restrict__ V2,
                                                   int* __restrict__ counts,
                                                   int n_nodes) {
    int i = blockIdx.x * 256 + threadIdx.x;
    if (i < N_CH * N_CH) {
        int k = i >> 7, o = i & 127;
        float w1 = W[o * 256 + k];
        float w2 = W[o * 256 + 128 + k];
        V1[i] = w1 - w2;
        V2[i] = w2;
    }
    if (i < n_nodes) counts[i] = 0;
}

// ---------------------------------------------------------------------------
// K1: A = x @ V1, Bm = x @ V2 fused (share x reads). fp32 VALU GEMM.
// Block: 256 threads, 32 nodes per block, each thread = (o, node-half),
// computes 16 nodes x 1 out x 2 matrices = 32 accumulators.
// x tile staged in LDS; per-(i,k) xs reads are wave-broadcast (same address).
// ---------------------------------------------------------------------------
__global__ __launch_bounds__(256) void gemm_kernel(const float* __restrict__ x,
                                                   const float* __restrict__ V1,
                                                   const float* __restrict__ V2,
                                                   float* __restrict__ A,
                                                   float* __restrict__ Bm,
                                                   int n_nodes) {
    __shared__ float xs[32][N_CH];      // 16 KB
    const int n0 = blockIdx.x * 32;
    const int tid = threadIdx.x;

    if (n0 + 32 <= n_nodes) {
        const float4* xg = (const float4*)(x + (size_t)n0 * N_CH);
        float4* xsv = (float4*)&xs[0][0];
        #pragma unroll
        for (int i = 0; i < 4; ++i) xsv[tid + i * 256] = xg[tid + i * 256];
    } else {
        for (int i = tid; i < 32 * N_CH; i += 256) {
            int n = n0 + (i >> 7);
            (&xs[0][0])[i] = (n < n_nodes) ? x[(size_t)n * N_CH + (i & 127)] : 0.f;
        }
    }
    __syncthreads();

    const int o  = tid & 127;
    const int nh = tid >> 7;            // 0 or 1
    float acc1[16], acc2[16];
    #pragma unroll
    for (int i = 0; i < 16; ++i) { acc1[i] = 0.f; acc2[i] = 0.f; }

    const float* xrow = &xs[nh * 16][0];
    for (int k4 = 0; k4 < N_CH; k4 += 4) {
        float w1[4], w2[4];
        #pragma unroll
        for (int j = 0; j < 4; ++j) {
            w1[j] = V1[(k4 + j) * N_CH + o];
            w2[j] = V2[(k4 + j) * N_CH + o];
        }
        #pragma unroll
        for (int i = 0; i < 16; ++i) {
            float4 xv = *(const float4*)&xrow[i * N_CH + k4];
            acc1[i] = fmaf(xv.x, w1[0], acc1[i]); acc2[i] = fmaf(xv.x, w2[0], acc2[i]);
            acc1[i] = fmaf(xv.y, w1[1], acc1[i]); acc2[i] = fmaf(xv.y, w2[1], acc2[i]);
            acc1[i] = fmaf(xv.z, w1[2], acc1[i]); acc2[i] = fmaf(xv.z, w2[2], acc2[i]);
            acc1[i] = fmaf(xv.w, w1[3], acc1[i]); acc2[i] = fmaf(xv.w, w2[3], acc2[i]);
        }
    }

    #pragma unroll
    for (int i = 0; i < 16; ++i) {
        int n = n0 + nh * 16 + i;
        if (n < n_nodes) {
            A [(size_t)n * N_CH + o] = acc1[i];
            Bm[(size_t)n * N_CH + o] = acc2[i];
        }
    }
}

// ---------------------------------------------------------------------------
// K2: histogram of dst
// ---------------------------------------------------------------------------
__global__ __launch_bounds__(256) void hist_kernel(const int* __restrict__ dst,
                                                   int* __restrict__ counts,
                                                   int n_edges) {
    int e = blockIdx.x * 256 + threadIdx.x;
    if (e < n_edges) atomicAdd(&counts[dst[e]], 1);
}

// ---------------------------------------------------------------------------
// K3: single-block exclusive scan over counts -> offsets[n+1], cursor copy
// ---------------------------------------------------------------------------
__global__ __launch_bounds__(1024) void scan_kernel(const int* __restrict__ counts,
                                                    int* __restrict__ offsets,
                                                    int* __restrict__ cursor,
                                                    int n) {
    __shared__ int tmp[1024];
    __shared__ int carry_s;
    const int tid = threadIdx.x;
    if (tid == 0) carry_s = 0;
    __syncthreads();
    for (int base = 0; base < n; base += 1024) {
        int v = (base + tid < n) ? counts[base + tid] : 0;
        tmp[tid] = v;
        __syncthreads();
        #pragma unroll
        for (int off = 1; off < 1024; off <<= 1) {
            int t = (tid >= off) ? tmp[tid - off] : 0;
            __syncthreads();
            tmp[tid] += t;
            __syncthreads();
        }
        int excl = tmp[tid] - v + carry_s;
        if (base + tid < n) { offsets[base + tid] = excl; cursor[base + tid] = excl; }
        __syncthreads();
        if (tid == 1023) carry_s += tmp[1023];
        __syncthreads();
    }
    if (tid == 0) offsets[n] = carry_s;
}

// ---------------------------------------------------------------------------
// K4: CSR fill — bucket src indices by dst
// ---------------------------------------------------------------------------
__global__ __launch_bounds__(256) void fill_kernel(const int* __restrict__ src,
                                                   const int* __restrict__ dst,
                                                   int* __restrict__ cursor,
                                                   int* __restrict__ eidx,
                                                   int n_edges) {
    int e = blockIdx.x * 256 + threadIdx.x;
    if (e < n_edges) {
        int pos = atomicAdd(&cursor[dst[e]], 1);
        eidx[pos] = src[e];
    }
}

// ---------------------------------------------------------------------------
// K5: per-node gather-max over neighbor rows of Bm; epilogue adds A + b.
// One block (128 threads = channels) per node. Neighbor indices chunked
// through LDS; Bm row reads are fully coalesced 512 B, L2/L3 resident.
// ---------------------------------------------------------------------------
__global__ __launch_bounds__(128) void gather_kernel(const float* __restrict__ A,
                                                     const float* __restrict__ Bm,
                                                     const float* __restrict__ b,
                                                     const int* __restrict__ offsets,
                                                     const int* __restrict__ eidx,
                                                     float* __restrict__ out,
                                                     int n_nodes) {
    __shared__ int sidx[128];
    const int n = blockIdx.x;
    const int c = threadIdx.x;
    const int beg = offsets[n], end = offsets[n + 1];

    float m0 = -INFINITY, m1 = -INFINITY, m2 = -INFINITY, m3 = -INFINITY;
    for (int base = beg; base < end; base += 128) {
        int p = base + c;
        if (p < end) sidx[c] = eidx[p];
        __syncthreads();
        int cnt = min(128, end - base);
        int q = 0;
        for (; q + 4 <= cnt; q += 4) {
            m0 = fmaxf(m0, Bm[(size_t)sidx[q + 0] * N_CH + c]);
            m1 = fmaxf(m1, Bm[(size_t)sidx[q + 1] * N_CH + c]);
            m2 = fmaxf(m2, Bm[(size_t)sidx[q + 2] * N_CH + c]);
            m3 = fmaxf(m3, Bm[(size_t)sidx[q + 3] * N_CH + c]);
        }
        for (; q < cnt; ++q)
            m0 = fmaxf(m0, Bm[(size_t)sidx[q] * N_CH + c]);
        __syncthreads();
    }
    float m = fmaxf(fmaxf(m0, m1), fmaxf(m2, m3));
    float r = (end > beg) ? (A[(size_t)n * N_CH + c] + b[c] + m) : 0.f;
    out[(size_t)n * N_CH + c] = r;
}

// ---------------------------------------------------------------------------
extern "C" void kernel_launch(void* const* d_in, const int* in_sizes, int n_in,
                              void* d_out, int out_size, void* d_ws, size_t ws_size,
                              hipStream_t stream) {
    const float* x = (const float*)d_in[0];
    const float* W = (const float*)d_in[1];
    const float* b = (const float*)d_in[2];
    const int*   ei = (const int*)d_in[3];

    const int n_nodes = in_sizes[0] / N_CH;   // 10000
    const int n_edges = in_sizes[3] / 2;      // 640000
    const int* src = ei;
    const int* dst = ei + n_edges;
    float* out = (float*)d_out;

    // workspace carve-up (256 B aligned)
    char* ws = (char*)d_ws;
    size_t off = 0;
    auto alloc = [&](size_t bytes) -> void* {
        void* p = ws + off;
        off += (bytes + 255) & ~(size_t)255;
        return p;
    };
    float* V1      = (float*)alloc((size_t)N_CH * N_CH * 4);
    float* V2      = (float*)alloc((size_t)N_CH * N_CH * 4);
    float* A       = (float*)alloc((size_t)n_nodes * N_CH * 4);
    float* Bm      = (float*)alloc((size_t)n_nodes * N_CH * 4);
    int*   counts  = (int*)alloc((size_t)n_nodes * 4);
    int*   offsets = (int*)alloc((size_t)(n_nodes + 1) * 4);
    int*   cursor  = (int*)alloc((size_t)n_nodes * 4);
    int*   eidx    = (int*)alloc((size_t)n_edges * 4);
    (void)ws_size; (void)n_in; (void)out_size;

    prep_kernel<<<(N_CH * N_CH + 255) / 256, 256, 0, stream>>>(W, V1, V2, counts, n_nodes);
    gemm_kernel<<<(n_nodes + 31) / 32, 256, 0, stream>>>(x, V1, V2, A, Bm, n_nodes);
    hist_kernel<<<(n_edges + 255) / 256, 256, 0, stream>>>(dst, counts, n_edges);
    scan_kernel<<<1, 1024, 0, stream>>>(counts, offsets, cursor, n_nodes);
    fill_kernel<<<(n_edges + 255) / 256, 256, 0, stream>>>(src, dst, cursor, eidx, n_edges);
    gather_kernel<<<n_nodes, 128, 0, stream>>>(A, Bm, b, offsets, eidx, out, n_nodes);
}

// Round 2
// 143.873 us; speedup vs baseline: 1.6627x; 1.6627x over previous
//
#include <hip/hip_runtime.h>
#include <math.h>

#define N_CH 128
#define NB_MAX 512          // max bucket count (n_nodes <= 16384 -> nb <= 512)
#define BIN_CHUNK 4096
#define BIN_T 512

// ---------------------------------------------------------------------------
// K0: build V1t[k*128+o] = W[o][k] - W[o][128+k], V2t[k*128+o] = W[o][128+k]
//     and zero the bucket histogram.
// ---------------------------------------------------------------------------
__global__ __launch_bounds__(256) void prep_kernel(const float* __restrict__ W,
                                                   float* __restrict__ V1,
                                                   float* __restrict__ V2,
                                                   int* __restrict__ binCount,
                                                   int nb) {
    int i = blockIdx.x * 256 + threadIdx.x;
    if (i < N_CH * N_CH) {
        int k = i >> 7, o = i & 127;
        float w1 = W[o * 256 + k];
        float w2 = W[o * 256 + 128 + k];
        V1[i] = w1 - w2;
        V2[i] = w2;
    }
    if (i < nb) binCount[i] = 0;
}

// ---------------------------------------------------------------------------
// K1: A = x @ V1, Bm = x @ V2 fused (share x reads). fp32 VALU GEMM.
// ---------------------------------------------------------------------------
__global__ __launch_bounds__(256) void gemm_kernel(const float* __restrict__ x,
                                                   const float* __restrict__ V1,
                                                   const float* __restrict__ V2,
                                                   float* __restrict__ A,
                                                   float* __restrict__ Bm,
                                                   int n_nodes) {
    __shared__ float xs[32][N_CH];      // 16 KB
    const int n0 = blockIdx.x * 32;
    const int tid = threadIdx.x;

    if (n0 + 32 <= n_nodes) {
        const float4* xg = (const float4*)(x + (size_t)n0 * N_CH);
        float4* xsv = (float4*)&xs[0][0];
        #pragma unroll
        for (int i = 0; i < 4; ++i) xsv[tid + i * 256] = xg[tid + i * 256];
    } else {
        for (int i = tid; i < 32 * N_CH; i += 256) {
            int n = n0 + (i >> 7);
            (&xs[0][0])[i] = (n < n_nodes) ? x[(size_t)n * N_CH + (i & 127)] : 0.f;
        }
    }
    __syncthreads();

    const int o  = tid & 127;
    const int nh = tid >> 7;            // 0 or 1
    float acc1[16], acc2[16];
    #pragma unroll
    for (int i = 0; i < 16; ++i) { acc1[i] = 0.f; acc2[i] = 0.f; }

    const float* xrow = &xs[nh * 16][0];
    for (int k4 = 0; k4 < N_CH; k4 += 4) {
        float w1[4], w2[4];
        #pragma unroll
        for (int j = 0; j < 4; ++j) {
            w1[j] = V1[(k4 + j) * N_CH + o];
            w2[j] = V2[(k4 + j) * N_CH + o];
        }
        #pragma unroll
        for (int i = 0; i < 16; ++i) {
            float4 xv = *(const float4*)&xrow[i * N_CH + k4];
            acc1[i] = fmaf(xv.x, w1[0], acc1[i]); acc2[i] = fmaf(xv.x, w2[0], acc2[i]);
            acc1[i] = fmaf(xv.y, w1[1], acc1[i]); acc2[i] = fmaf(xv.y, w2[1], acc2[i]);
            acc1[i] = fmaf(xv.z, w1[2], acc1[i]); acc2[i] = fmaf(xv.z, w2[2], acc2[i]);
            acc1[i] = fmaf(xv.w, w1[3], acc1[i]); acc2[i] = fmaf(xv.w, w2[3], acc2[i]);
        }
    }

    #pragma unroll
    for (int i = 0; i < 16; ++i) {
        int n = n0 + nh * 16 + i;
        if (n < n_nodes) {
            A [(size_t)n * N_CH + o] = acc1[i];
            Bm[(size_t)n * N_CH + o] = acc2[i];
        }
    }
}

// ---------------------------------------------------------------------------
// K2: bucket histogram (bucket = dst >> 5). LDS-staged, few global atomics.
// ---------------------------------------------------------------------------
__global__ __launch_bounds__(256) void bhist_kernel(const int* __restrict__ dst,
                                                    int* __restrict__ binCount,
                                                    int n_edges, int nb) {
    __shared__ int h[NB_MAX];
    const int tid = threadIdx.x;
    for (int i = tid; i < nb; i += 256) h[i] = 0;
    __syncthreads();
    const int base = blockIdx.x * BIN_CHUNK;
    const int cnt = min(BIN_CHUNK, n_edges - base);
    for (int j = tid; j < cnt; j += 256)
        atomicAdd(&h[dst[base + j] >> 5], 1);
    __syncthreads();
    for (int i = tid; i < nb; i += 256)
        if (h[i]) atomicAdd(&binCount[i], h[i]);
}

// ---------------------------------------------------------------------------
// K3: exclusive scan over nb (<=512) bucket counts -> binOff[nb+1], binCursor
// ---------------------------------------------------------------------------
__global__ __launch_bounds__(512) void bscan_kernel(const int* __restrict__ binCount,
                                                    int* __restrict__ binOff,
                                                    int* __restrict__ binCursor,
                                                    int nb) {
    __shared__ int t[512];
    const int tid = threadIdx.x;
    int v = (tid < nb) ? binCount[tid] : 0;
    t[tid] = v;
    __syncthreads();
    #pragma unroll
    for (int off = 1; off < 512; off <<= 1) {
        int u = (tid >= off) ? t[tid - off] : 0;
        __syncthreads();
        t[tid] += u;
        __syncthreads();
    }
    if (tid < nb) {
        int excl = t[tid] - v;
        binOff[tid] = excl;
        binCursor[tid] = excl;
    }
    if (tid == 0) binOff[nb] = t[nb - 1];
}

// ---------------------------------------------------------------------------
// K4: bin scatter. Each block counting-sorts BIN_CHUNK edges by bucket in LDS,
// reserves global per-bucket ranges (1 atomic/bucket/block), writes packed
// (dst&31)<<14 | src words in bucket-ordered runs (mostly coalesced).
// Requires n_nodes < 16384 (src fits 14 bits).
// ---------------------------------------------------------------------------
__global__ __launch_bounds__(BIN_T) void bin_kernel(const int* __restrict__ src,
                                                    const int* __restrict__ dst,
                                                    int* __restrict__ binCursor,
                                                    unsigned int* __restrict__ binned,
                                                    int n_edges, int nb) {
    __shared__ unsigned int   lpk[BIN_CHUNK];      // 16 KB
    __shared__ unsigned short lbk[BIN_CHUNK];      // 8 KB
    __shared__ int sc[512];                        // scan temp
    __shared__ int lhist[NB_MAX], lexcl[NB_MAX], lcur[NB_MAX], bbase[NB_MAX];

    const int tid = threadIdx.x;
    const int base = blockIdx.x * BIN_CHUNK;
    const int cnt = min(BIN_CHUNK, n_edges - base);

    for (int i = tid; i < nb; i += BIN_T) lhist[i] = 0;
    __syncthreads();

    unsigned int vreg[BIN_CHUNK / BIN_T];
    unsigned short breg[BIN_CHUNK / BIN_T];
    int nloc = 0;
    for (int j = tid; j < cnt; j += BIN_T) {
        int s = src[base + j];
        int d = dst[base + j];
        int b = d >> 5;
        vreg[nloc] = ((unsigned int)(d & 31) << 14) | (unsigned int)s;
        breg[nloc] = (unsigned short)b;
        ++nloc;
        atomicAdd(&lhist[b], 1);
    }
    __syncthreads();

    // scan bucket counts (Hillis-Steele over 512)
    int v = (tid < nb) ? lhist[tid] : 0;
    sc[tid] = v;
    __syncthreads();
    #pragma unroll
    for (int off = 1; off < 512; off <<= 1) {
        int u = (tid >= off) ? sc[tid - off] : 0;
        __syncthreads();
        sc[tid] += u;
        __syncthreads();
    }
    if (tid < nb) {
        int excl = sc[tid] - v;
        lexcl[tid] = excl;
        lcur[tid] = excl;
    }
    __syncthreads();

    // local scatter into bucket-sorted LDS order
    for (int k = 0; k < nloc; ++k) {
        int b = breg[k];
        int p = atomicAdd(&lcur[b], 1);
        lpk[p] = vreg[k];
        lbk[p] = (unsigned short)b;
    }
    __syncthreads();

    // reserve global ranges
    for (int b = tid; b < nb; b += BIN_T) {
        int c = lhist[b];
        if (c) bbase[b] = atomicAdd(&binCursor[b], c);
    }
    __syncthreads();

    // ordered write-out: consecutive i in same bucket -> consecutive global
    for (int i = tid; i < cnt; i += BIN_T) {
        int b = lbk[i];
        binned[bbase[b] + (i - lexcl[b])] = lpk[i];
    }
}

// ---------------------------------------------------------------------------
// K5: per-bucket CSR build. One block per bucket (32 nodes): local hist/scan
// in LDS, eidx scatter confined to the bucket's contiguous ~8 KB window,
// global offsets[] emitted directly (binOff[b] + local exclusive scan).
// ---------------------------------------------------------------------------
__global__ __launch_bounds__(256) void build_kernel(const unsigned int* __restrict__ binned,
                                                    const int* __restrict__ binOff,
                                                    int* __restrict__ offsets,
                                                    int* __restrict__ eidx,
                                                    int n_nodes, int nb) {
    __shared__ int lhist[32], lexcl[33], lcur[32];
    const int b = blockIdx.x;
    const int tid = threadIdx.x;
    const int rbeg = binOff[b], rend = binOff[b + 1];

    if (tid < 32) { lhist[tid] = 0; lcur[tid] = 0; }
    __syncthreads();
    for (int i = rbeg + tid; i < rend; i += 256)
        atomicAdd(&lhist[binned[i] >> 14], 1);
    __syncthreads();
    if (tid == 0) {
        int s = 0;
        for (int k = 0; k < 32; ++k) { lexcl[k] = s; s += lhist[k]; }
        lexcl[32] = s;
    }
    __syncthreads();
    if (tid < 32) {
        int n = b * 32 + tid;
        if (n < n_nodes) offsets[n] = rbeg + lexcl[tid];
    }
    if (b == nb - 1 && tid == 0) offsets[n_nodes] = rend;
    for (int i = rbeg + tid; i < rend; i += 256) {
        unsigned int w = binned[i];
        int d5 = (int)(w >> 14);
        int r = atomicAdd(&lcur[d5], 1);
        eidx[rbeg + lexcl[d5] + r] = (int)(w & 16383u);
    }
}

// ---------------------------------------------------------------------------
// K6: per-node gather-max over neighbor rows of Bm; epilogue adds A + b.
// ---------------------------------------------------------------------------
__global__ __launch_bounds__(128) void gather_kernel(const float* __restrict__ A,
                                                     const float* __restrict__ Bm,
                                                     const float* __restrict__ b,
                                                     const int* __restrict__ offsets,
                                                     const int* __restrict__ eidx,
                                                     float* __restrict__ out,
                                                     int n_nodes) {
    __shared__ int sidx[128];
    const int n = blockIdx.x;
    const int c = threadIdx.x;
    const int beg = offsets[n], end = offsets[n + 1];

    float m[8];
    #pragma unroll
    for (int i = 0; i < 8; ++i) m[i] = -INFINITY;

    for (int base = beg; base < end; base += 128) {
        int p = base + c;
        if (p < end) sidx[c] = eidx[p];
        __syncthreads();
        int cnt = min(128, end - base);
        int q = 0;
        for (; q + 8 <= cnt; q += 8) {
            #pragma unroll
            for (int i = 0; i < 8; ++i)
                m[i] = fmaxf(m[i], Bm[(size_t)sidx[q + i] * N_CH + c]);
        }
        for (; q < cnt; ++q)
            m[0] = fmaxf(m[0], Bm[(size_t)sidx[q] * N_CH + c]);
        __syncthreads();
    }
    float mm = fmaxf(fmaxf(fmaxf(m[0], m[1]), fmaxf(m[2], m[3])),
                     fmaxf(fmaxf(m[4], m[5]), fmaxf(m[6], m[7])));
    float r = (end > beg) ? (A[(size_t)n * N_CH + c] + b[c] + mm) : 0.f;
    out[(size_t)n * N_CH + c] = r;
}

// ---------------------------------------------------------------------------
extern "C" void kernel_launch(void* const* d_in, const int* in_sizes, int n_in,
                              void* d_out, int out_size, void* d_ws, size_t ws_size,
                              hipStream_t stream) {
    const float* x = (const float*)d_in[0];
    const float* W = (const float*)d_in[1];
    const float* b = (const float*)d_in[2];
    const int*   ei = (const int*)d_in[3];

    const int n_nodes = in_sizes[0] / N_CH;   // 10000
    const int n_edges = in_sizes[3] / 2;      // 640000
    const int nb = (n_nodes + 31) >> 5;       // 313 buckets of 32 nodes
    const int* src = ei;
    const int* dst = ei + n_edges;
    float* out = (float*)d_out;

    // workspace carve-up (256 B aligned)
    char* ws = (char*)d_ws;
    size_t off = 0;
    auto alloc = [&](size_t bytes) -> void* {
        void* p = ws + off;
        off += (bytes + 255) & ~(size_t)255;
        return p;
    };
    float* V1        = (float*)alloc((size_t)N_CH * N_CH * 4);
    float* V2        = (float*)alloc((size_t)N_CH * N_CH * 4);
    float* A         = (float*)alloc((size_t)n_nodes * N_CH * 4);
    float* Bm        = (float*)alloc((size_t)n_nodes * N_CH * 4);
    int*   binCount  = (int*)alloc((size_t)nb * 4);
    int*   binOff    = (int*)alloc((size_t)(nb + 1) * 4);
    int*   binCursor = (int*)alloc((size_t)nb * 4);
    unsigned int* binned = (unsigned int*)alloc((size_t)n_edges * 4);
    int*   offsets   = (int*)alloc((size_t)(n_nodes + 1) * 4);
    int*   eidx      = (int*)alloc((size_t)n_edges * 4);
    (void)ws_size; (void)n_in; (void)out_size;

    const int nbin_blocks = (n_edges + BIN_CHUNK - 1) / BIN_CHUNK;

    prep_kernel <<<(N_CH * N_CH + 255) / 256, 256, 0, stream>>>(W, V1, V2, binCount, nb);
    gemm_kernel <<<(n_nodes + 31) / 32, 256, 0, stream>>>(x, V1, V2, A, Bm, n_nodes);
    bhist_kernel<<<nbin_blocks, 256, 0, stream>>>(dst, binCount, n_edges, nb);
    bscan_kernel<<<1, 512, 0, stream>>>(binCount, binOff, binCursor, nb);
    bin_kernel  <<<nbin_blocks, BIN_T, 0, stream>>>(src, dst, binCursor, binned, n_edges, nb);
    build_kernel<<<nb, 256, 0, stream>>>(binned, binOff, offsets, eidx, n_nodes, nb);
    gather_kernel<<<n_nodes, 128, 0, stream>>>(A, Bm, b, offsets, eidx, out, n_nodes);
}